// Round 1
// baseline (764.519 us; speedup 1.0000x reference)
//
#include <hip/hip_runtime.h>
#include <stdint.h>

#define HDIM 2048
#define FFND 8192
#define NHEAD 16
#define HDHEAD 128
#define TSEQ 2048
#define MTOK 4096

typedef short s16;
typedef __bf16 bf16;
typedef __attribute__((ext_vector_type(8))) __bf16 bf16x8;
typedef __attribute__((ext_vector_type(4))) float f32x4;

__device__ __forceinline__ unsigned short f2bf(float f) {
    union { float f; unsigned u; } a; a.f = f;
    unsigned r = a.u + 0x7fffu + ((a.u >> 16) & 1u);
    return (unsigned short)(r >> 16);
}

__device__ __forceinline__ void gload_lds16(const s16* g, s16* l) {
    __builtin_amdgcn_global_load_lds(
        (const __attribute__((address_space(1))) void*)g,
        (__attribute__((address_space(3))) void*)l, 16, 0, 0);
}

// ---------------- transpose + fp32->bf16 convert: out[n][k] = bf16(in[k][n]) ----------------
__global__ __launch_bounds__(256) void transpose_convert(
    const float* __restrict__ in, s16* __restrict__ out, int K, int N)
{
    __shared__ float tile[32][33];
    int n0 = blockIdx.x * 32, k0 = blockIdx.y * 32;
    int tx = threadIdx.x, ty = threadIdx.y;
    #pragma unroll
    for (int r = 0; r < 32; r += 8)
        tile[ty + r][tx] = in[(size_t)(k0 + ty + r) * N + n0 + tx];
    __syncthreads();
    #pragma unroll
    for (int r = 0; r < 32; r += 8)
        out[(size_t)(n0 + ty + r) * K + k0 + tx] = (s16)f2bf(tile[tx][ty + r]);
}

// ---------------- LayerNorm (fp32 in -> bf16 out), one row per block ----------------
__global__ __launch_bounds__(256) void ln_kernel(
    const float* __restrict__ x, const float* __restrict__ gam,
    const float* __restrict__ bet, s16* __restrict__ out)
{
    int row = blockIdx.x;
    int t = threadIdx.x;
    const float4* xr = (const float4*)(x + (size_t)row * HDIM);
    float4 v0 = xr[t], v1 = xr[t + 256];
    float s = v0.x + v0.y + v0.z + v0.w + v1.x + v1.y + v1.z + v1.w;
    #pragma unroll
    for (int m = 1; m < 64; m <<= 1) s += __shfl_xor(s, m);
    __shared__ float red[8];
    int wid = t >> 6, lane = t & 63;
    if (lane == 0) red[wid] = s;
    __syncthreads();
    float mean = (red[0] + red[1] + red[2] + red[3]) * (1.0f / HDIM);
    float d0 = v0.x - mean, d1 = v0.y - mean, d2 = v0.z - mean, d3 = v0.w - mean;
    float d4 = v1.x - mean, d5 = v1.y - mean, d6 = v1.z - mean, d7 = v1.w - mean;
    float vs = d0*d0 + d1*d1 + d2*d2 + d3*d3 + d4*d4 + d5*d5 + d6*d6 + d7*d7;
    #pragma unroll
    for (int m = 1; m < 64; m <<= 1) vs += __shfl_xor(vs, m);
    if (lane == 0) red[4 + wid] = vs;
    __syncthreads();
    float var = (red[4] + red[5] + red[6] + red[7]) * (1.0f / HDIM);
    float rinv = rsqrtf(var + 1e-5f);
    const float4* gm = (const float4*)gam;
    const float4* bt = (const float4*)bet;
    float4 g0 = gm[t], g1 = gm[t + 256], b0 = bt[t], b1 = bt[t + 256];
    s16* orow = out + (size_t)row * HDIM;
    float y0 = d0 * rinv * g0.x + b0.x, y1 = d1 * rinv * g0.y + b0.y;
    float y2 = d2 * rinv * g0.z + b0.z, y3 = d3 * rinv * g0.w + b0.w;
    float y4 = d4 * rinv * g1.x + b1.x, y5 = d5 * rinv * g1.y + b1.y;
    float y6 = d6 * rinv * g1.z + b1.z, y7 = d7 * rinv * g1.w + b1.w;
    uint2 o0, o1;
    o0.x = (unsigned)f2bf(y0) | ((unsigned)f2bf(y1) << 16);
    o0.y = (unsigned)f2bf(y2) | ((unsigned)f2bf(y3) << 16);
    o1.x = (unsigned)f2bf(y4) | ((unsigned)f2bf(y5) << 16);
    o1.y = (unsigned)f2bf(y6) | ((unsigned)f2bf(y7) << 16);
    *(uint2*)(orow + t * 4) = o0;
    *(uint2*)(orow + 1024 + t * 4) = o1;
}

// ---------------- GEMM: C[M][N] = A[M][K](bf16) * Bt[N][K](bf16)^T + bias, fused epilogue ----
// EPI 0: qkv scatter (ob=q [b,h,t,d], ob2=k [b,h,t,d], ob3=v transposed [b,h,d,t])
// EPI 1: of[m*N+n] = acc + bias[n] + resid[m*N+n]  (fp32 out)
// EPI 2: ob[m*N+n] = bf16(gelu(acc + bias[n]))
template<int EPI>
__global__ __launch_bounds__(256) void gemm_bt(
    const s16* __restrict__ A, const s16* __restrict__ Bt,
    const float* __restrict__ bias, int M, int N, int K,
    float* __restrict__ of, const float* __restrict__ resid,
    s16* __restrict__ ob, s16* __restrict__ ob2, s16* __restrict__ ob3)
{
    __shared__ __attribute__((aligned(16))) s16 As[2][128 * 32];
    __shared__ __attribute__((aligned(16))) s16 Bs[2][128 * 32];
    int t = threadIdx.x;
    int wid = t >> 6, lane = t & 63;
    int wm = wid >> 1, wn = wid & 1;
    int c = lane & 15, g = lane >> 4;
    int n0 = blockIdx.x * 128, m0 = blockIdx.y * 128;

    int r4 = t >> 2, c4 = (t & 3) << 3;
    const s16* ga = A + (size_t)(m0 + r4) * K + c4;
    const s16* gb = Bt + (size_t)(n0 + r4) * K + c4;

    f32x4 zero = {0.f, 0.f, 0.f, 0.f};
    f32x4 acc[4][4];
    #pragma unroll
    for (int mi = 0; mi < 4; ++mi)
        #pragma unroll
        for (int ni = 0; ni < 4; ++ni) acc[mi][ni] = zero;

    int nk = K >> 5;
    {   // prologue: stage kt=0 into buffer 0
        s16* la = &As[0][0] + 8 * t;
        s16* lb = &Bs[0][0] + 8 * t;
        gload_lds16(ga, la); gload_lds16(ga + (size_t)64 * K, la + 2048);
        gload_lds16(gb, lb); gload_lds16(gb + (size_t)64 * K, lb + 2048);
    }
    for (int kt = 0; kt < nk; ++kt) {
        __syncthreads();   // staged buf[cur] complete (drains vmcnt)
        int cur = kt & 1;
        if (kt + 1 < nk) {
            const s16* ga2 = ga + (size_t)(kt + 1) * 32;
            const s16* gb2 = gb + (size_t)(kt + 1) * 32;
            s16* la2 = &As[cur ^ 1][0] + 8 * t;
            s16* lb2 = &Bs[cur ^ 1][0] + 8 * t;
            gload_lds16(ga2, la2); gload_lds16(ga2 + (size_t)64 * K, la2 + 2048);
            gload_lds16(gb2, lb2); gload_lds16(gb2 + (size_t)64 * K, lb2 + 2048);
        }
        const s16* Ac = &As[cur][0];
        const s16* Bc = &Bs[cur][0];
        bf16x8 af[4], bfr[4];
        #pragma unroll
        for (int mi = 0; mi < 4; ++mi)
            af[mi] = *(const bf16x8*)(Ac + (wm * 64 + mi * 16 + c) * 32 + g * 8);
        #pragma unroll
        for (int ni = 0; ni < 4; ++ni)
            bfr[ni] = *(const bf16x8*)(Bc + (wn * 64 + ni * 16 + c) * 32 + g * 8);
        #pragma unroll
        for (int mi = 0; mi < 4; ++mi)
            #pragma unroll
            for (int ni = 0; ni < 4; ++ni)
                acc[mi][ni] = __builtin_amdgcn_mfma_f32_16x16x32_bf16(
                    af[mi], bfr[ni], acc[mi][ni], 0, 0, 0);
    }

    // epilogue: lane (g,c) holds D[row=mi*16+4g+j][col=ni*16+c]
    #pragma unroll
    for (int mi = 0; mi < 4; ++mi) {
        #pragma unroll
        for (int ni = 0; ni < 4; ++ni) {
            int n = n0 + wn * 64 + ni * 16 + c;
            float bn = bias[n];
            f32x4 v = acc[mi][ni];
            #pragma unroll
            for (int j = 0; j < 4; ++j) {
                int m = m0 + wm * 64 + mi * 16 + g * 4 + j;
                float val = v[j] + bn;
                if constexpr (EPI == 0) {
                    int part = n >> 11, rr = n & 2047, hh = rr >> 7, dd = rr & 127;
                    int bb = m >> 11, tt = m & 2047;
                    s16 bv = (s16)f2bf(val);
                    size_t bh = (size_t)(bb * NHEAD + hh);
                    if (part == 0)      ob [(bh * TSEQ + tt) * HDHEAD + dd] = bv;
                    else if (part == 1) ob2[(bh * TSEQ + tt) * HDHEAD + dd] = bv;
                    else                ob3[(bh * HDHEAD + dd) * TSEQ + tt] = bv;
                } else if constexpr (EPI == 1) {
                    size_t idx = (size_t)m * N + n;
                    of[idx] = val + resid[idx];
                } else {
                    float zz = 1.5957691216057308f * (val + 0.044715f * val * val * val);
                    float ge = val / (1.0f + __expf(-zz));
                    ob[(size_t)m * N + n] = (s16)f2bf(ge);
                }
            }
        }
    }
}

// ---------------- causal flash attention, swapped-operand (S^T = K*Q^T) ----------------
// q,k: [b][h][t][d] bf16;  v: [b][h][d][t] bf16 (pre-transposed);  y: [b][t][h*d] bf16
__global__ __launch_bounds__(256) void attn_kernel(
    const s16* __restrict__ qb, const s16* __restrict__ kbf,
    const s16* __restrict__ vbf, s16* __restrict__ yb)
{
    __shared__ __attribute__((aligned(16))) s16 Kl[64 * 128];
    __shared__ __attribute__((aligned(16))) s16 Vl[128 * 64];
    int bid = blockIdx.x;
    int qt = bid & 31;
    int bh = bid >> 5;
    int q0 = qt << 6;
    int t = threadIdx.x;
    int wid = t >> 6, lane = t & 63;
    int c = lane & 15, g = lane >> 4;

    // Q fragments held in registers: lane needs Q[q0+wid*16+c][ds*32 + 8g .. +8]
    const s16* qrow = qb + ((size_t)bh * TSEQ + q0 + wid * 16 + c) * HDHEAD;
    bf16x8 qf[4];
    #pragma unroll
    for (int ds = 0; ds < 4; ++ds) qf[ds] = *(const bf16x8*)(qrow + ds * 32 + g * 8);

    f32x4 zero = {0.f, 0.f, 0.f, 0.f};
    f32x4 acc_o[8];
    #pragma unroll
    for (int o = 0; o < 8; ++o) acc_o[o] = zero;
    float mrun = -INFINITY, lrun = 0.0f;
    const float sc = 0.08838834764831843f;  // 1/sqrt(128)

    int tr = t >> 4, tcb = (t & 15) << 4;   // K staging: row base, byte col
    int vr = t >> 3, vcb = (t & 7) << 4;    // V staging
    const s16* ksrc = kbf + (size_t)bh * TSEQ * HDHEAD;
    const s16* vsrc = vbf + (size_t)bh * HDHEAD * TSEQ;
    int qg = q0 + wid * 16 + c;

    for (int kt = 0; kt <= qt; ++kt) {
        __syncthreads();
        #pragma unroll
        for (int rr = 0; rr < 4; ++rr) {   // K tile [64][128], XOR-swizzled rows
            int row = tr + rr * 16;
            bf16x8 kv = *(const bf16x8*)(ksrc + (size_t)(kt * 64 + row) * HDHEAD + (tcb >> 1));
            *(bf16x8*)((char*)Kl + row * 256 + (tcb ^ ((row & 7) << 4))) = kv;
        }
        #pragma unroll
        for (int rr = 0; rr < 4; ++rr) {   // V^T tile [128][64]
            int row = vr + rr * 32;
            bf16x8 vv = *(const bf16x8*)(vsrc + (size_t)row * TSEQ + kt * 64 + (vcb >> 1));
            *(bf16x8*)((char*)Vl + row * 128 + (vcb ^ ((row & 7) << 4))) = vv;
        }
        __syncthreads();

        // S^T[k][q]: A=K rows, B=Q^T
        f32x4 sacc[4];
        #pragma unroll
        for (int kb2 = 0; kb2 < 4; ++kb2) sacc[kb2] = zero;
        #pragma unroll
        for (int ds = 0; ds < 4; ++ds) {
            #pragma unroll
            for (int kb2 = 0; kb2 < 4; ++kb2) {
                int krow = kb2 * 16 + c;
                bf16x8 kf = *(const bf16x8*)((char*)Kl + krow * 256 +
                                ((ds * 64 + g * 16) ^ ((krow & 7) << 4)));
                sacc[kb2] = __builtin_amdgcn_mfma_f32_16x16x32_bf16(kf, qf[ds], sacc[kb2], 0, 0, 0);
            }
        }
        // online softmax; lane holds S^T[kb2*16+4g+j][q=c]
        float pv[16];
        float mt = -INFINITY;
        bool diag = (kt == qt);
        #pragma unroll
        for (int kb2 = 0; kb2 < 4; ++kb2) {
            #pragma unroll
            for (int j = 0; j < 4; ++j) {
                float s = sacc[kb2][j] * sc;
                if (diag && (kt * 64 + kb2 * 16 + g * 4 + j) > qg) s = -INFINITY;
                pv[kb2 * 4 + j] = s;
                mt = fmaxf(mt, s);
            }
        }
        mt = fmaxf(mt, __shfl_xor(mt, 16));
        mt = fmaxf(mt, __shfl_xor(mt, 32));
        float mnew = fmaxf(mrun, mt);
        float corr = __expf(mrun - mnew);
        float ls = 0.0f;
        #pragma unroll
        for (int i = 0; i < 16; ++i) { float p = __expf(pv[i] - mnew); pv[i] = p; ls += p; }
        ls += __shfl_xor(ls, 16);
        ls += __shfl_xor(ls, 32);
        lrun = lrun * corr + ls;
        mrun = mnew;
        #pragma unroll
        for (int o = 0; o < 8; ++o)
            #pragma unroll
            for (int j = 0; j < 4; ++j) acc_o[o][j] *= corr;

        // pack P to bf16 pairs (k-adjacent), redistribute to B-frag layout via shfl
        unsigned dpk[8];
        #pragma unroll
        for (int kb2 = 0; kb2 < 4; ++kb2) {
            dpk[kb2 * 2]     = (unsigned)f2bf(pv[kb2 * 4 + 0]) | ((unsigned)f2bf(pv[kb2 * 4 + 1]) << 16);
            dpk[kb2 * 2 + 1] = (unsigned)f2bf(pv[kb2 * 4 + 2]) | ((unsigned)f2bf(pv[kb2 * 4 + 3]) << 16);
        }
        int srcA = ((g & 1) << 5) + c;   // lane 16*(2*(g&1)) + c
        int srcB = srcA + 16;
        #pragma unroll
        for (int s2 = 0; s2 < 2; ++s2) {
            unsigned lo0 = (unsigned)__shfl((int)dpk[(2 * s2) * 2 + 0], srcA);
            unsigned hi0 = (unsigned)__shfl((int)dpk[(2 * s2 + 1) * 2 + 0], srcA);
            unsigned lo1 = (unsigned)__shfl((int)dpk[(2 * s2) * 2 + 1], srcA);
            unsigned hi1 = (unsigned)__shfl((int)dpk[(2 * s2 + 1) * 2 + 1], srcA);
            unsigned lo2 = (unsigned)__shfl((int)dpk[(2 * s2) * 2 + 0], srcB);
            unsigned hi2 = (unsigned)__shfl((int)dpk[(2 * s2 + 1) * 2 + 0], srcB);
            unsigned lo3 = (unsigned)__shfl((int)dpk[(2 * s2) * 2 + 1], srcB);
            unsigned hi3 = (unsigned)__shfl((int)dpk[(2 * s2 + 1) * 2 + 1], srcB);
            union { unsigned u[4]; bf16x8 v; } pf;
            pf.u[0] = (g < 2) ? lo0 : hi0;
            pf.u[1] = (g < 2) ? lo1 : hi1;
            pf.u[2] = (g < 2) ? lo2 : hi2;
            pf.u[3] = (g < 2) ? lo3 : hi3;
            #pragma unroll
            for (int o = 0; o < 8; ++o) {
                int vrow = o * 16 + c;
                bf16x8 vf = *(const bf16x8*)((char*)Vl + vrow * 128 +
                                ((s2 * 64 + g * 16) ^ ((vrow & 7) << 4)));
                acc_o[o] = __builtin_amdgcn_mfma_f32_16x16x32_bf16(vf, pf.v, acc_o[o], 0, 0, 0);
            }
        }
    }

    // write O = O^T/l : lane (g,c) has O^T[o*16+4g+j][q=c]
    float inv = 1.0f / lrun;
    int bb = bh >> 4, hh = bh & 15;
    s16* yp = yb + ((size_t)bb * TSEQ + q0 + wid * 16 + c) * HDIM + hh * HDHEAD;
    #pragma unroll
    for (int o = 0; o < 8; ++o) {
        int d = o * 16 + g * 4;
        unsigned p0 = (unsigned)f2bf(acc_o[o][0] * inv) | ((unsigned)f2bf(acc_o[o][1] * inv) << 16);
        unsigned p1 = (unsigned)f2bf(acc_o[o][2] * inv) | ((unsigned)f2bf(acc_o[o][3] * inv) << 16);
        *(unsigned*)(yp + d) = p0;
        *(unsigned*)(yp + d + 2) = p1;
    }
}

extern "C" void kernel_launch(void* const* d_in, const int* in_sizes, int n_in,
                              void* d_out, int out_size, void* d_ws, size_t ws_size,
                              hipStream_t stream)
{
    const float* x     = (const float*)d_in[0];
    const float* ln1g  = (const float*)d_in[1];
    const float* ln1b  = (const float*)d_in[2];
    const float* wattn = (const float*)d_in[3];
    const float* battn = (const float*)d_in[4];
    const float* wproj = (const float*)d_in[5];
    const float* bproj = (const float*)d_in[6];
    const float* ln2g  = (const float*)d_in[7];
    const float* ln2b  = (const float*)d_in[8];
    const float* wfc   = (const float*)d_in[9];
    const float* bfc   = (const float*)d_in[10];
    const float* wfc2  = (const float*)d_in[11];
    const float* bfc2  = (const float*)d_in[12];
    float* out = (float*)d_out;

    s16* ws   = (s16*)d_ws;
    s16* wT   = ws;                        // 16,777,216 elems (max weight^T)
    s16* qbuf = wT + 16777216;             // 8,388,608
    s16* kbuf = qbuf + 8388608;            // 8,388,608
    s16* vbuf = kbuf + 8388608;            // 8,388,608 (transposed V)
    s16* hbuf = vbuf + 8388608;            // 8,388,608 (LN1 out; reused as attn y)
    s16* ybuf  = hbuf;                     // reuse: h dead after QKV GEMM
    s16* h2buf = qbuf;                     // reuse: q dead after attention
    s16* gbuf  = kbuf;                     // reuse: k+v dead after attention (16.7M elems)

    // 1) LN1: x -> h (bf16)
    ln_kernel<<<4096, 256, 0, stream>>>(x, ln1g, ln1b, hbuf);
    // 2) w_attn^T (bf16) ; qkv = h @ w_attn + b ; scatter q/k/v (v transposed)
    transpose_convert<<<dim3(6144 / 32, 2048 / 32), dim3(32, 8), 0, stream>>>(wattn, wT, 2048, 6144);
    gemm_bt<0><<<dim3(6144 / 128, 4096 / 128), 256, 0, stream>>>(
        hbuf, wT, battn, MTOK, 6144, 2048, nullptr, nullptr, qbuf, kbuf, vbuf);
    // 3) causal flash attention -> y (bf16, [b][t][C])
    attn_kernel<<<1024, 256, 0, stream>>>(qbuf, kbuf, vbuf, ybuf);
    // 4) proj: x2 = x + y @ w_proj + b  (fp32, into d_out)
    transpose_convert<<<dim3(2048 / 32, 2048 / 32), dim3(32, 8), 0, stream>>>(wproj, wT, 2048, 2048);
    gemm_bt<1><<<dim3(2048 / 128, 4096 / 128), 256, 0, stream>>>(
        ybuf, wT, bproj, MTOK, 2048, 2048, out, x, nullptr, nullptr, nullptr);
    // 5) LN2: x2 -> h2 (bf16)
    ln_kernel<<<4096, 256, 0, stream>>>(out, ln2g, ln2b, h2buf);
    // 6) fc: gbuf = gelu(h2 @ w_fc + b) (bf16)
    transpose_convert<<<dim3(8192 / 32, 2048 / 32), dim3(32, 8), 0, stream>>>(wfc, wT, 2048, 8192);
    gemm_bt<2><<<dim3(8192 / 128, 4096 / 128), 256, 0, stream>>>(
        h2buf, wT, bfc, MTOK, 8192, 2048, nullptr, nullptr, gbuf, nullptr, nullptr);
    // 7) fc2: out = x2 + g @ w_fc2 + b (fp32; reads+overwrites d_out per-element)
    transpose_convert<<<dim3(2048 / 32, 8192 / 32), dim3(32, 8), 0, stream>>>(wfc2, wT, 8192, 2048);
    gemm_bt<1><<<dim3(2048 / 128, 4096 / 128), 256, 0, stream>>>(
        gbuf, wT, bfc2, MTOK, 2048, 8192, out, out, nullptr, nullptr, nullptr);
}

// Round 2
// 709.892 us; speedup vs baseline: 1.0770x; 1.0770x over previous
//
#include <hip/hip_runtime.h>
#include <stdint.h>

#define HDIM 2048
#define FFND 8192
#define NHEAD 16
#define HDHEAD 128
#define TSEQ 2048
#define MTOK 4096

typedef short s16;
typedef __bf16 bf16;
typedef __attribute__((ext_vector_type(8))) __bf16 bf16x8;
typedef __attribute__((ext_vector_type(4))) float f32x4;

__device__ __forceinline__ unsigned short f2bf(float f) {
    union { float f; unsigned u; } a; a.f = f;
    unsigned r = a.u + 0x7fffu + ((a.u >> 16) & 1u);
    return (unsigned short)(r >> 16);
}

__device__ __forceinline__ void gload_lds16(const s16* g, s16* l) {
    __builtin_amdgcn_global_load_lds(
        (const __attribute__((address_space(1))) void*)g,
        (__attribute__((address_space(3))) void*)l, 16, 0, 0);
}

// ---------------- transpose + fp32->bf16 convert: out[n][k] = bf16(in[k][n]) ----------------
__global__ __launch_bounds__(256) void transpose_convert(
    const float* __restrict__ in, s16* __restrict__ out, int K, int N)
{
    __shared__ float tile[32][33];
    int n0 = blockIdx.x * 32, k0 = blockIdx.y * 32;
    int tx = threadIdx.x, ty = threadIdx.y;
    #pragma unroll
    for (int r = 0; r < 32; r += 8)
        tile[ty + r][tx] = in[(size_t)(k0 + ty + r) * N + n0 + tx];
    __syncthreads();
    #pragma unroll
    for (int r = 0; r < 32; r += 8)
        out[(size_t)(n0 + ty + r) * K + k0 + tx] = (s16)f2bf(tile[tx][ty + r]);
}

// ---------------- LayerNorm (fp32 in -> bf16 out), one row per block ----------------
__global__ __launch_bounds__(256) void ln_kernel(
    const float* __restrict__ x, const float* __restrict__ gam,
    const float* __restrict__ bet, s16* __restrict__ out)
{
    int row = blockIdx.x;
    int t = threadIdx.x;
    const float4* xr = (const float4*)(x + (size_t)row * HDIM);
    float4 v0 = xr[t], v1 = xr[t + 256];
    float s = v0.x + v0.y + v0.z + v0.w + v1.x + v1.y + v1.z + v1.w;
    #pragma unroll
    for (int m = 1; m < 64; m <<= 1) s += __shfl_xor(s, m);
    __shared__ float red[8];
    int wid = t >> 6, lane = t & 63;
    if (lane == 0) red[wid] = s;
    __syncthreads();
    float mean = (red[0] + red[1] + red[2] + red[3]) * (1.0f / HDIM);
    float d0 = v0.x - mean, d1 = v0.y - mean, d2 = v0.z - mean, d3 = v0.w - mean;
    float d4 = v1.x - mean, d5 = v1.y - mean, d6 = v1.z - mean, d7 = v1.w - mean;
    float vs = d0*d0 + d1*d1 + d2*d2 + d3*d3 + d4*d4 + d5*d5 + d6*d6 + d7*d7;
    #pragma unroll
    for (int m = 1; m < 64; m <<= 1) vs += __shfl_xor(vs, m);
    if (lane == 0) red[4 + wid] = vs;
    __syncthreads();
    float var = (red[4] + red[5] + red[6] + red[7]) * (1.0f / HDIM);
    float rinv = rsqrtf(var + 1e-5f);
    const float4* gm = (const float4*)gam;
    const float4* bt = (const float4*)bet;
    float4 g0 = gm[t], g1 = gm[t + 256], b0 = bt[t], b1 = bt[t + 256];
    s16* orow = out + (size_t)row * HDIM;
    float y0 = d0 * rinv * g0.x + b0.x, y1 = d1 * rinv * g0.y + b0.y;
    float y2 = d2 * rinv * g0.z + b0.z, y3 = d3 * rinv * g0.w + b0.w;
    float y4 = d4 * rinv * g1.x + b1.x, y5 = d5 * rinv * g1.y + b1.y;
    float y6 = d6 * rinv * g1.z + b1.z, y7 = d7 * rinv * g1.w + b1.w;
    uint2 o0, o1;
    o0.x = (unsigned)f2bf(y0) | ((unsigned)f2bf(y1) << 16);
    o0.y = (unsigned)f2bf(y2) | ((unsigned)f2bf(y3) << 16);
    o1.x = (unsigned)f2bf(y4) | ((unsigned)f2bf(y5) << 16);
    o1.y = (unsigned)f2bf(y6) | ((unsigned)f2bf(y7) << 16);
    *(uint2*)(orow + t * 4) = o0;
    *(uint2*)(orow + 1024 + t * 4) = o1;
}

// ---------------- GEMM: C[M][N] = A[M][K](bf16) * Bt[N][K](bf16)^T + bias, fused epilogue ----
// 3-slot LDS pipeline, counted vmcnt(4) (never 0 in loop), T2 XOR-swizzle, T5 setprio,
// T1 XCD-aware block swizzle.
// EPI 0: qkv scatter via LDS bounce (ob=q [b,h,t,d], ob2=k [b,h,t,d], ob3=v [b,h,d,t])
// EPI 1: of[m*N+n] = acc + bias[n] + resid[m*N+n]  (fp32 out)
// EPI 2: ob[m*N+n] = bf16(gelu(acc + bias[n]))
template<int EPI>
__global__ __launch_bounds__(256, 3) void gemm_bt(
    const s16* __restrict__ A, const s16* __restrict__ Bt,
    const float* __restrict__ bias, int M, int N, int K,
    float* __restrict__ of, const float* __restrict__ resid,
    s16* __restrict__ ob, s16* __restrict__ ob2, s16* __restrict__ ob3)
{
    __shared__ __attribute__((aligned(16))) s16 smem[3 * 4096 * 2];  // 48 KB
    s16* As0 = smem;            // 3 slots x 4096 elems (A tiles, 128x32 swizzled)
    s16* Bs0 = smem + 12288;    // 3 slots x 4096 elems (B tiles)

    int t = threadIdx.x;
    int wid = t >> 6, lane = t & 63;
    int wm = wid >> 1, wn = wid & 1;
    int c = lane & 15, g = lane >> 4;

    // T1: bijective XCD swizzle (all grids have nwg % 8 == 0)
    int gx = gridDim.x;
    int wg = blockIdx.y * gx + blockIdx.x;
    int nwg = gx * gridDim.y;
    int cpx = nwg >> 3;
    wg = (wg & 7) * cpx + (wg >> 3);
    int n0 = (wg % gx) * 128;
    int m0 = (wg / gx) * 128;

    // staging: thread t covers physical LDS bytes [16t,16t+16) and [16t+4096, +16)
    // T2 swizzle: phys = logical ^ (((row>>1)&3)<<4)  => source col slot pre-permuted
    int r = t >> 2;
    int slot = (t & 3) ^ ((t >> 3) & 3);
    const s16* ga = A + (size_t)(m0 + r) * K + slot * 8;
    const s16* gb = Bt + (size_t)(n0 + r) * K + slot * 8;

    f32x4 zero = {0.f, 0.f, 0.f, 0.f};
    f32x4 acc[4][4];
    #pragma unroll
    for (int mi = 0; mi < 4; ++mi)
        #pragma unroll
        for (int ni = 0; ni < 4; ++ni) acc[mi][ni] = zero;

    int nk = K >> 5;

#define STAGE(sl, ktv) { \
    const s16* a_ = ga + (size_t)(ktv) * 32; \
    const s16* b_ = gb + (size_t)(ktv) * 32; \
    s16* la_ = As0 + (sl) * 4096 + 8 * t; \
    s16* lb_ = Bs0 + (sl) * 4096 + 8 * t; \
    gload_lds16(a_, la_); gload_lds16(a_ + (size_t)64 * K, la_ + 2048); \
    gload_lds16(b_, lb_); gload_lds16(b_ + (size_t)64 * K, lb_ + 2048); }

    // prologue: tiles 0,1 in flight; wait tile 0, keep tile 1 in flight
    STAGE(0, 0)
    STAGE(1, 1)
    asm volatile("s_waitcnt vmcnt(4)" ::: "memory");
    __builtin_amdgcn_s_barrier();

    int swb = (g ^ ((c >> 1) & 3)) << 4;   // swizzled 16B slot for fragment reads
    int cs = 0, ss = 2;
    for (int kt = 0; kt < nk; ++kt) {
        bool more = (kt + 2 < nk);
        if (more) STAGE(ss, kt + 2)
        const char* Ac = (const char*)(As0 + cs * 4096);
        const char* Bc = (const char*)(Bs0 + cs * 4096);
        bf16x8 af[4], bfr[4];
        #pragma unroll
        for (int mi = 0; mi < 4; ++mi)
            af[mi] = *(const bf16x8*)(Ac + (wm * 64 + mi * 16 + c) * 64 + swb);
        #pragma unroll
        for (int ni = 0; ni < 4; ++ni)
            bfr[ni] = *(const bf16x8*)(Bc + (wn * 64 + ni * 16 + c) * 64 + swb);
        __builtin_amdgcn_s_setprio(1);
        #pragma unroll
        for (int mi = 0; mi < 4; ++mi)
            #pragma unroll
            for (int ni = 0; ni < 4; ++ni)
                acc[mi][ni] = __builtin_amdgcn_mfma_f32_16x16x32_bf16(
                    af[mi], bfr[ni], acc[mi][ni], 0, 0, 0);
        __builtin_amdgcn_s_setprio(0);
        if (more) asm volatile("s_waitcnt vmcnt(4)" ::: "memory");
        else      asm volatile("s_waitcnt vmcnt(0)" ::: "memory");
        __builtin_amdgcn_s_barrier();
        cs = (cs == 2) ? 0 : cs + 1;
        ss = (ss == 2) ? 0 : ss + 1;
    }
#undef STAGE

    // epilogue: lane (g,c) holds D[row=mi*16+4g+j][col=ni*16+c]
    if constexpr (EPI == 0) {
        // bounce C-tile through LDS (stride 136 elems: 16B-aligned rows, spread banks)
        s16* LT = smem;
        #pragma unroll
        for (int mi = 0; mi < 4; ++mi) {
            #pragma unroll
            for (int ni = 0; ni < 4; ++ni) {
                int nl = wn * 64 + ni * 16 + c;
                float bn = bias[n0 + nl];
                #pragma unroll
                for (int j = 0; j < 4; ++j) {
                    int ml = wm * 64 + mi * 16 + g * 4 + j;
                    LT[ml * 136 + nl] = (s16)f2bf(acc[mi][ni][j] + bn);
                }
            }
        }
        __syncthreads();
        int part = n0 >> 11;
        int hh = (n0 >> 7) & 15;
        int bb = m0 >> 11;
        int tt0 = m0 & 2047;
        size_t bh = (size_t)bb * NHEAD + hh;
        if (part < 2) {
            s16* dst = (part == 0 ? ob : ob2) + (bh * TSEQ + tt0) * HDHEAD;
            int rr = t >> 1, c0 = (t & 1) * 64;
            #pragma unroll
            for (int k2 = 0; k2 < 8; ++k2)
                *(bf16x8*)(dst + rr * HDHEAD + c0 + k2 * 8) =
                    *(const bf16x8*)(LT + rr * 136 + c0 + k2 * 8);
        } else {
            s16* dst = ob3 + bh * HDHEAD * TSEQ;
            int dd = t >> 1, e0 = (t & 1) * 64;
            #pragma unroll
            for (int k2 = 0; k2 < 8; ++k2) {
                union { s16 v[8]; bf16x8 x; } u;
                #pragma unroll
                for (int e = 0; e < 8; ++e) u.v[e] = LT[(e0 + k2 * 8 + e) * 136 + dd];
                *(bf16x8*)(dst + (size_t)dd * TSEQ + tt0 + e0 + k2 * 8) = u.x;
            }
        }
    } else {
        #pragma unroll
        for (int mi = 0; mi < 4; ++mi) {
            #pragma unroll
            for (int ni = 0; ni < 4; ++ni) {
                int n = n0 + wn * 64 + ni * 16 + c;
                float bn = bias[n];
                f32x4 v = acc[mi][ni];
                #pragma unroll
                for (int j = 0; j < 4; ++j) {
                    int m = m0 + wm * 64 + mi * 16 + g * 4 + j;
                    float val = v[j] + bn;
                    if constexpr (EPI == 1) {
                        size_t idx = (size_t)m * N + n;
                        of[idx] = val + resid[idx];
                    } else {
                        float zz = 1.5957691216057308f * (val + 0.044715f * val * val * val);
                        float ge = val / (1.0f + __expf(-zz));
                        ob[(size_t)m * N + n] = (s16)f2bf(ge);
                    }
                }
            }
        }
    }
}

// ---------------- causal flash attention, swapped-operand (S^T = K*Q^T) ----------------
// q,k: [b][h][t][d] bf16;  v: [b][h][d][t] bf16 (pre-transposed);  y: [b][t][h*d] bf16
__global__ __launch_bounds__(256) void attn_kernel(
    const s16* __restrict__ qb, const s16* __restrict__ kbf,
    const s16* __restrict__ vbf, s16* __restrict__ yb)
{
    __shared__ __attribute__((aligned(16))) s16 Kl[64 * 128];
    __shared__ __attribute__((aligned(16))) s16 Vl[128 * 64];
    int bid0 = blockIdx.x;
    int bid = ((bid0 & 7) << 7) | (bid0 >> 3);   // XCD swizzle (1024 blocks)
    int qt = bid & 31;
    int bh = bid >> 5;
    int q0 = qt << 6;
    int t = threadIdx.x;
    int wid = t >> 6, lane = t & 63;
    int c = lane & 15, g = lane >> 4;

    const s16* qrow = qb + ((size_t)bh * TSEQ + q0 + wid * 16 + c) * HDHEAD;
    bf16x8 qf[4];
    #pragma unroll
    for (int ds = 0; ds < 4; ++ds) qf[ds] = *(const bf16x8*)(qrow + ds * 32 + g * 8);

    f32x4 zero = {0.f, 0.f, 0.f, 0.f};
    f32x4 acc_o[8];
    #pragma unroll
    for (int o = 0; o < 8; ++o) acc_o[o] = zero;
    float mrun = -INFINITY, lrun = 0.0f;
    const float sc = 0.08838834764831843f;  // 1/sqrt(128)

    int tr = t >> 4, tcb = (t & 15) << 4;
    int vr = t >> 3, vcb = (t & 7) << 4;
    const s16* ksrc = kbf + (size_t)bh * TSEQ * HDHEAD;
    const s16* vsrc = vbf + (size_t)bh * HDHEAD * TSEQ;
    int qg = q0 + wid * 16 + c;

    for (int kt = 0; kt <= qt; ++kt) {
        __syncthreads();
        #pragma unroll
        for (int rr = 0; rr < 4; ++rr) {
            int row = tr + rr * 16;
            bf16x8 kv = *(const bf16x8*)(ksrc + (size_t)(kt * 64 + row) * HDHEAD + (tcb >> 1));
            *(bf16x8*)((char*)Kl + row * 256 + (tcb ^ ((row & 7) << 4))) = kv;
        }
        #pragma unroll
        for (int rr = 0; rr < 4; ++rr) {
            int row = vr + rr * 32;
            bf16x8 vv = *(const bf16x8*)(vsrc + (size_t)row * TSEQ + kt * 64 + (vcb >> 1));
            *(bf16x8*)((char*)Vl + row * 128 + (vcb ^ ((row & 7) << 4))) = vv;
        }
        __syncthreads();

        f32x4 sacc[4];
        #pragma unroll
        for (int kb2 = 0; kb2 < 4; ++kb2) sacc[kb2] = zero;
        #pragma unroll
        for (int ds = 0; ds < 4; ++ds) {
            #pragma unroll
            for (int kb2 = 0; kb2 < 4; ++kb2) {
                int krow = kb2 * 16 + c;
                bf16x8 kf = *(const bf16x8*)((char*)Kl + krow * 256 +
                                ((ds * 64 + g * 16) ^ ((krow & 7) << 4)));
                sacc[kb2] = __builtin_amdgcn_mfma_f32_16x16x32_bf16(kf, qf[ds], sacc[kb2], 0, 0, 0);
            }
        }
        float pv[16];
        float mt = -INFINITY;
        bool diag = (kt == qt);
        #pragma unroll
        for (int kb2 = 0; kb2 < 4; ++kb2) {
            #pragma unroll
            for (int j = 0; j < 4; ++j) {
                float s = sacc[kb2][j] * sc;
                if (diag && (kt * 64 + kb2 * 16 + g * 4 + j) > qg) s = -INFINITY;
                pv[kb2 * 4 + j] = s;
                mt = fmaxf(mt, s);
            }
        }
        mt = fmaxf(mt, __shfl_xor(mt, 16));
        mt = fmaxf(mt, __shfl_xor(mt, 32));
        float mnew = fmaxf(mrun, mt);
        float corr = __expf(mrun - mnew);
        float ls = 0.0f;
        #pragma unroll
        for (int i = 0; i < 16; ++i) { float p = __expf(pv[i] - mnew); pv[i] = p; ls += p; }
        ls += __shfl_xor(ls, 16);
        ls += __shfl_xor(ls, 32);
        lrun = lrun * corr + ls;
        mrun = mnew;
        #pragma unroll
        for (int o = 0; o < 8; ++o)
            #pragma unroll
            for (int j = 0; j < 4; ++j) acc_o[o][j] *= corr;

        unsigned dpk[8];
        #pragma unroll
        for (int kb2 = 0; kb2 < 4; ++kb2) {
            dpk[kb2 * 2]     = (unsigned)f2bf(pv[kb2 * 4 + 0]) | ((unsigned)f2bf(pv[kb2 * 4 + 1]) << 16);
            dpk[kb2 * 2 + 1] = (unsigned)f2bf(pv[kb2 * 4 + 2]) | ((unsigned)f2bf(pv[kb2 * 4 + 3]) << 16);
        }
        int srcA = ((g & 1) << 5) + c;
        int srcB = srcA + 16;
        #pragma unroll
        for (int s2 = 0; s2 < 2; ++s2) {
            unsigned lo0 = (unsigned)__shfl((int)dpk[(2 * s2) * 2 + 0], srcA);
            unsigned hi0 = (unsigned)__shfl((int)dpk[(2 * s2 + 1) * 2 + 0], srcA);
            unsigned lo1 = (unsigned)__shfl((int)dpk[(2 * s2) * 2 + 1], srcA);
            unsigned hi1 = (unsigned)__shfl((int)dpk[(2 * s2 + 1) * 2 + 1], srcA);
            unsigned lo2 = (unsigned)__shfl((int)dpk[(2 * s2) * 2 + 0], srcB);
            unsigned hi2 = (unsigned)__shfl((int)dpk[(2 * s2 + 1) * 2 + 0], srcB);
            unsigned lo3 = (unsigned)__shfl((int)dpk[(2 * s2) * 2 + 1], srcB);
            unsigned hi3 = (unsigned)__shfl((int)dpk[(2 * s2 + 1) * 2 + 1], srcB);
            union { unsigned u[4]; bf16x8 v; } pf;
            pf.u[0] = (g < 2) ? lo0 : hi0;
            pf.u[1] = (g < 2) ? lo1 : hi1;
            pf.u[2] = (g < 2) ? lo2 : hi2;
            pf.u[3] = (g < 2) ? lo3 : hi3;
            #pragma unroll
            for (int o = 0; o < 8; ++o) {
                int vrow = o * 16 + c;
                bf16x8 vf = *(const bf16x8*)((char*)Vl + vrow * 128 +
                                ((s2 * 64 + g * 16) ^ ((vrow & 7) << 4)));
                acc_o[o] = __builtin_amdgcn_mfma_f32_16x16x32_bf16(vf, pf.v, acc_o[o], 0, 0, 0);
            }
        }
    }

    float inv = 1.0f / lrun;
    int bb = bh >> 4, hh = bh & 15;
    s16* yp = yb + ((size_t)bb * TSEQ + q0 + wid * 16 + c) * HDIM + hh * HDHEAD;
    #pragma unroll
    for (int o = 0; o < 8; ++o) {
        int d = o * 16 + g * 4;
        unsigned p0 = (unsigned)f2bf(acc_o[o][0] * inv) | ((unsigned)f2bf(acc_o[o][1] * inv) << 16);
        unsigned p1 = (unsigned)f2bf(acc_o[o][2] * inv) | ((unsigned)f2bf(acc_o[o][3] * inv) << 16);
        *(unsigned*)(yp + d) = p0;
        *(unsigned*)(yp + d + 2) = p1;
    }
}

extern "C" void kernel_launch(void* const* d_in, const int* in_sizes, int n_in,
                              void* d_out, int out_size, void* d_ws, size_t ws_size,
                              hipStream_t stream)
{
    const float* x     = (const float*)d_in[0];
    const float* ln1g  = (const float*)d_in[1];
    const float* ln1b  = (const float*)d_in[2];
    const float* wattn = (const float*)d_in[3];
    const float* battn = (const float*)d_in[4];
    const float* wproj = (const float*)d_in[5];
    const float* bproj = (const float*)d_in[6];
    const float* ln2g  = (const float*)d_in[7];
    const float* ln2b  = (const float*)d_in[8];
    const float* wfc   = (const float*)d_in[9];
    const float* bfc   = (const float*)d_in[10];
    const float* wfc2  = (const float*)d_in[11];
    const float* bfc2  = (const float*)d_in[12];
    float* out = (float*)d_out;

    s16* ws   = (s16*)d_ws;
    s16* wT   = ws;                        // 16,777,216 elems (max weight^T)
    s16* qbuf = wT + 16777216;             // 8,388,608
    s16* kbuf = qbuf + 8388608;            // 8,388,608
    s16* vbuf = kbuf + 8388608;            // 8,388,608 (transposed V)
    s16* hbuf = vbuf + 8388608;            // 8,388,608 (LN1 out; reused as attn y)
    s16* ybuf  = hbuf;                     // reuse: h dead after QKV GEMM
    s16* h2buf = qbuf;                     // reuse: q dead after attention
    s16* gbuf  = kbuf;                     // reuse: k+v dead after attention (16.7M elems)

    // 1) LN1: x -> h (bf16)
    ln_kernel<<<4096, 256, 0, stream>>>(x, ln1g, ln1b, hbuf);
    // 2) w_attn^T (bf16) ; qkv = h @ w_attn + b ; scatter q/k/v (v transposed)
    transpose_convert<<<dim3(6144 / 32, 2048 / 32), dim3(32, 8), 0, stream>>>(wattn, wT, 2048, 6144);
    gemm_bt<0><<<dim3(6144 / 128, 4096 / 128), 256, 0, stream>>>(
        hbuf, wT, battn, MTOK, 6144, 2048, nullptr, nullptr, qbuf, kbuf, vbuf);
    // 3) causal flash attention -> y (bf16, [b][t][C])
    attn_kernel<<<1024, 256, 0, stream>>>(qbuf, kbuf, vbuf, ybuf);
    // 4) proj: x2 = x + y @ w_proj + b  (fp32, into d_out)
    transpose_convert<<<dim3(2048 / 32, 2048 / 32), dim3(32, 8), 0, stream>>>(wproj, wT, 2048, 2048);
    gemm_bt<1><<<dim3(2048 / 128, 4096 / 128), 256, 0, stream>>>(
        ybuf, wT, bproj, MTOK, 2048, 2048, out, x, nullptr, nullptr, nullptr);
    // 5) LN2: x2 -> h2 (bf16)
    ln_kernel<<<4096, 256, 0, stream>>>(out, ln2g, ln2b, h2buf);
    // 6) fc: gbuf = gelu(h2 @ w_fc + b) (bf16)
    transpose_convert<<<dim3(8192 / 32, 2048 / 32), dim3(32, 8), 0, stream>>>(wfc, wT, 2048, 8192);
    gemm_bt<2><<<dim3(8192 / 128, 4096 / 128), 256, 0, stream>>>(
        h2buf, wT, bfc, MTOK, 8192, 2048, nullptr, nullptr, gbuf, nullptr, nullptr);
    // 7) fc2: out = x2 + g @ w_fc2 + b (fp32; reads+overwrites d_out per-element)
    transpose_convert<<<dim3(2048 / 32, 8192 / 32), dim3(32, 8), 0, stream>>>(wfc2, wT, 8192, 2048);
    gemm_bt<1><<<dim3(2048 / 128, 4096 / 128), 256, 0, stream>>>(
        gbuf, wT, bfc2, MTOK, 2048, 8192, out, out, nullptr, nullptr, nullptr);
}

// Round 3
// 653.285 us; speedup vs baseline: 1.1703x; 1.0867x over previous
//
#include <hip/hip_runtime.h>
#include <stdint.h>

#define HDIM 2048
#define FFND 8192
#define NHEAD 16
#define HDHEAD 128
#define TSEQ 2048
#define MTOK 4096

typedef short s16;
typedef __bf16 bf16;
typedef __attribute__((ext_vector_type(8))) __bf16 bf16x8;
typedef __attribute__((ext_vector_type(4))) float f32x4;

__device__ __forceinline__ unsigned short f2bf(float f) {
    union { float f; unsigned u; } a; a.f = f;
    unsigned r = a.u + 0x7fffu + ((a.u >> 16) & 1u);
    return (unsigned short)(r >> 16);
}

__device__ __forceinline__ void gload_lds16(const s16* g, s16* l) {
    __builtin_amdgcn_global_load_lds(
        (const __attribute__((address_space(1))) void*)g,
        (__attribute__((address_space(3))) void*)l, 16, 0, 0);
}

// ---------------- transpose + fp32->bf16 convert: out[n][k] = bf16(in[k][n]) ----------------
__global__ __launch_bounds__(256) void transpose_convert(
    const float* __restrict__ in, s16* __restrict__ out, int K, int N)
{
    __shared__ float tile[32][33];
    int n0 = blockIdx.x * 32, k0 = blockIdx.y * 32;
    int tx = threadIdx.x, ty = threadIdx.y;
    #pragma unroll
    for (int r = 0; r < 32; r += 8)
        tile[ty + r][tx] = in[(size_t)(k0 + ty + r) * N + n0 + tx];
    __syncthreads();
    #pragma unroll
    for (int r = 0; r < 32; r += 8)
        out[(size_t)(n0 + ty + r) * K + k0 + tx] = (s16)f2bf(tile[tx][ty + r]);
}

// ---------------- LayerNorm (fp32 in -> bf16 out), one row per block ----------------
__global__ __launch_bounds__(256) void ln_kernel(
    const float* __restrict__ x, const float* __restrict__ gam,
    const float* __restrict__ bet, s16* __restrict__ out)
{
    int row = blockIdx.x;
    int t = threadIdx.x;
    const float4* xr = (const float4*)(x + (size_t)row * HDIM);
    float4 v0 = xr[t], v1 = xr[t + 256];
    float s = v0.x + v0.y + v0.z + v0.w + v1.x + v1.y + v1.z + v1.w;
    #pragma unroll
    for (int m = 1; m < 64; m <<= 1) s += __shfl_xor(s, m);
    __shared__ float red[8];
    int wid = t >> 6, lane = t & 63;
    if (lane == 0) red[wid] = s;
    __syncthreads();
    float mean = (red[0] + red[1] + red[2] + red[3]) * (1.0f / HDIM);
    float d0 = v0.x - mean, d1 = v0.y - mean, d2 = v0.z - mean, d3 = v0.w - mean;
    float d4 = v1.x - mean, d5 = v1.y - mean, d6 = v1.z - mean, d7 = v1.w - mean;
    float vs = d0*d0 + d1*d1 + d2*d2 + d3*d3 + d4*d4 + d5*d5 + d6*d6 + d7*d7;
    #pragma unroll
    for (int m = 1; m < 64; m <<= 1) vs += __shfl_xor(vs, m);
    if (lane == 0) red[4 + wid] = vs;
    __syncthreads();
    float var = (red[4] + red[5] + red[6] + red[7]) * (1.0f / HDIM);
    float rinv = rsqrtf(var + 1e-5f);
    const float4* gm = (const float4*)gam;
    const float4* bt = (const float4*)bet;
    float4 g0 = gm[t], g1 = gm[t + 256], b0 = bt[t], b1 = bt[t + 256];
    s16* orow = out + (size_t)row * HDIM;
    float y0 = d0 * rinv * g0.x + b0.x, y1 = d1 * rinv * g0.y + b0.y;
    float y2 = d2 * rinv * g0.z + b0.z, y3 = d3 * rinv * g0.w + b0.w;
    float y4 = d4 * rinv * g1.x + b1.x, y5 = d5 * rinv * g1.y + b1.y;
    float y6 = d6 * rinv * g1.z + b1.z, y7 = d7 * rinv * g1.w + b1.w;
    uint2 o0, o1;
    o0.x = (unsigned)f2bf(y0) | ((unsigned)f2bf(y1) << 16);
    o0.y = (unsigned)f2bf(y2) | ((unsigned)f2bf(y3) << 16);
    o1.x = (unsigned)f2bf(y4) | ((unsigned)f2bf(y5) << 16);
    o1.y = (unsigned)f2bf(y6) | ((unsigned)f2bf(y7) << 16);
    *(uint2*)(orow + t * 4) = o0;
    *(uint2*)(orow + 1024 + t * 4) = o1;
}

// ---------------- 256-wide GEMM: C[M][N] = A[M][K] * Bt[N][K]^T + bias ----------------
// BM=256, BK=32, 8 waves (2x4), wave tile 128 x (BN/4). 4-slot LDS ring, counted
// vmcnt (never 0 mid-loop), involution swizzle (zero-conflict, validated r2),
// setprio around MFMA clusters, bijective XCD chunk swizzle.
// EPI 0: qkv scatter via LDS bounce (BN=256 only)
// EPI 1: of = acc + bias + resid (fp32)   EPI 2: ob = bf16(gelu(acc + bias))
template<int BN, int EPI>
__global__ __launch_bounds__(512, 2) void gemm256(
    const s16* __restrict__ A, const s16* __restrict__ Bt,
    const float* __restrict__ bias, int M, int N, int K,
    float* __restrict__ of, const float* __restrict__ resid,
    s16* __restrict__ ob, s16* __restrict__ ob2, s16* __restrict__ ob3)
{
    constexpr int WN = BN / 4;          // 64 or 32
    constexpr int NR = WN / 16;         // 4 or 2
    constexpr int BSLOT = BN * 32;      // elems per B slot
    constexpr int LPT = (BN == 256) ? 4 : 3;   // gloads per thread per K-tile
    __shared__ __attribute__((aligned(16))) s16 smem[4 * 8192 + 4 * BSLOT];
    s16* Asl = smem;
    s16* Bsl = smem + 4 * 8192;

    int t = threadIdx.x;
    int wid = t >> 6, lane = t & 63;
    int wm = wid >> 2, wn = wid & 3;
    int c = lane & 15, g = lane >> 4;

    int gx = gridDim.x;
    int wg = blockIdx.y * gx + blockIdx.x;
    int nwg = gx * gridDim.y;
    wg = (wg & 7) * (nwg >> 3) + (wg >> 3);
    int n0 = (wg % gx) * BN;
    int m0 = (wg / gx) * 256;

    // bias to regs BEFORE staging (keeps vmcnt counting clean)
    float bn[NR];
    #pragma unroll
    for (int ni = 0; ni < NR; ++ni) bn[ni] = bias[n0 + wn * WN + ni * 16 + c];

    int swcol = ((t & 3) ^ ((t >> 3) & 3)) * 8;     // pre-swizzled source col
    const s16* gA = A + (size_t)(m0 + (t >> 2)) * K + swcol;
    const s16* gB = Bt + (size_t)(n0 + (t >> 2)) * K + swcol;

    auto stage = [&](int sl, int kt2) {
        const s16* a_ = gA + (size_t)kt2 * 32;
        s16* la_ = Asl + sl * 8192 + 8 * t;
        gload_lds16(a_, la_);
        gload_lds16(a_ + (size_t)128 * K, la_ + 4096);
        const s16* b_ = gB + (size_t)kt2 * 32;
        s16* lb_ = Bsl + sl * BSLOT + 8 * t;
        gload_lds16(b_, lb_);
        if constexpr (BN == 256) gload_lds16(b_ + (size_t)128 * K, lb_ + 4096);
    };

    f32x4 zero = {0.f, 0.f, 0.f, 0.f};
    f32x4 acc[8][NR];
    #pragma unroll
    for (int mi = 0; mi < 8; ++mi)
        #pragma unroll
        for (int ni = 0; ni < NR; ++ni) acc[mi][ni] = zero;

    int nk = K >> 5;
    stage(0, 0);
    stage(1, 1);
    asm volatile("s_waitcnt vmcnt(%0)" :: "i"(LPT) : "memory");
    __builtin_amdgcn_s_barrier();

    int swb = (g ^ ((c >> 1) & 3)) * 8;             // swizzled read slot (const/thread)
    for (int kt = 0; kt < nk; ++kt) {
        int cs = kt & 3;
        if (kt + 2 < nk) stage((kt + 2) & 3, kt + 2);
        const s16* Ac = Asl + cs * 8192;
        const s16* Bc = Bsl + cs * BSLOT;
        bf16x8 bfr[NR];
        #pragma unroll
        for (int ni = 0; ni < NR; ++ni)
            bfr[ni] = *(const bf16x8*)(Bc + (wn * WN + ni * 16 + c) * 32 + swb);
        bf16x8 af[4];
        #pragma unroll
        for (int mi = 0; mi < 4; ++mi)
            af[mi] = *(const bf16x8*)(Ac + (wm * 128 + mi * 16 + c) * 32 + swb);
        __builtin_amdgcn_s_setprio(1);
        #pragma unroll
        for (int mi = 0; mi < 4; ++mi)
            #pragma unroll
            for (int ni = 0; ni < NR; ++ni)
                acc[mi][ni] = __builtin_amdgcn_mfma_f32_16x16x32_bf16(
                    af[mi], bfr[ni], acc[mi][ni], 0, 0, 0);
        __builtin_amdgcn_s_setprio(0);
        #pragma unroll
        for (int mi = 0; mi < 4; ++mi)
            af[mi] = *(const bf16x8*)(Ac + (wm * 128 + 64 + mi * 16 + c) * 32 + swb);
        __builtin_amdgcn_s_setprio(1);
        #pragma unroll
        for (int mi = 0; mi < 4; ++mi)
            #pragma unroll
            for (int ni = 0; ni < NR; ++ni)
                acc[4 + mi][ni] = __builtin_amdgcn_mfma_f32_16x16x32_bf16(
                    af[mi], bfr[ni], acc[4 + mi][ni], 0, 0, 0);
        __builtin_amdgcn_s_setprio(0);
        if (kt + 2 < nk) { asm volatile("s_waitcnt vmcnt(%0)" :: "i"(LPT) : "memory"); }
        else             { asm volatile("s_waitcnt vmcnt(0)" ::: "memory"); }
        __builtin_amdgcn_s_barrier();
    }

    // epilogue: acc[mi][ni] row = wm*128 + (mi>>2)*64 + (mi&3)*16 + g*4 + j, col = wn*WN + ni*16 + c
    if constexpr (EPI == 0) {
        int part = n0 >> 11;
        int hh0 = (n0 & 2047) >> 7;
        int bb = m0 >> 11;
        int tt0 = m0 & 2047;
        s16* LT = smem;                 // 64 x 264 bounce buffer
        #pragma unroll
        for (int q = 0; q < 4; ++q) {
            if (q) __syncthreads();
            if (wm == (q >> 1)) {
                int mh = (q & 1) * 4;
                #pragma unroll
                for (int mi2 = 0; mi2 < 4; ++mi2)
                    #pragma unroll
                    for (int ni = 0; ni < 4; ++ni)
                        #pragma unroll
                        for (int j = 0; j < 4; ++j)
                            LT[(mi2 * 16 + g * 4 + j) * 264 + wn * 64 + ni * 16 + c] =
                                (s16)f2bf(acc[mh + mi2][ni][j] + bn[ni]);
            }
            __syncthreads();
            if (part < 2) {
                s16* dst = (part == 0 ? ob : ob2);
                int rr = t >> 3, c0 = (t & 7) * 32;
                int hh = hh0 + (c0 >> 7);
                size_t base = (((size_t)(bb * NHEAD + hh)) * TSEQ + tt0 + q * 64 + rr) * HDHEAD + (c0 & 127);
                #pragma unroll
                for (int k2 = 0; k2 < 4; ++k2)
                    *(bf16x8*)(dst + base + k2 * 8) = *(const bf16x8*)(LT + rr * 264 + c0 + k2 * 8);
            } else {
                int ddl = t >> 1, half = t & 1;
                int hh = hh0 + (ddl >> 7);
                size_t base = (((size_t)(bb * NHEAD + hh)) * HDHEAD + (ddl & 127)) * TSEQ + tt0 + q * 64 + half * 32;
                #pragma unroll
                for (int k2 = 0; k2 < 4; ++k2) {
                    union { s16 v[8]; bf16x8 x; } u;
                    #pragma unroll
                    for (int e = 0; e < 8; ++e) u.v[e] = LT[(half * 32 + k2 * 8 + e) * 264 + ddl];
                    *(bf16x8*)(ob3 + base + k2 * 8) = u.x;
                }
            }
        }
    } else {
        #pragma unroll
        for (int mi = 0; mi < 8; ++mi) {
            int ro = (mi >> 2) * 64 + (mi & 3) * 16 + g * 4;
            #pragma unroll
            for (int ni = 0; ni < NR; ++ni) {
                int n = n0 + wn * WN + ni * 16 + c;
                #pragma unroll
                for (int j = 0; j < 4; ++j) {
                    int m = m0 + wm * 128 + ro + j;
                    float val = acc[mi][ni][j] + bn[ni];
                    if constexpr (EPI == 1) {
                        size_t idx = (size_t)m * N + n;
                        of[idx] = val + resid[idx];
                    } else {
                        float zz = 1.5957691216057308f * (val + 0.044715f * val * val * val);
                        float ge = val / (1.0f + __expf(-zz));
                        ob[(size_t)m * N + n] = (s16)f2bf(ge);
                    }
                }
            }
        }
    }
}

// ---------------- causal flash attention, swapped-operand (S^T = K*Q^T) ----------------
__global__ __launch_bounds__(256) void attn_kernel(
    const s16* __restrict__ qb, const s16* __restrict__ kbf,
    const s16* __restrict__ vbf, s16* __restrict__ yb)
{
    __shared__ __attribute__((aligned(16))) s16 Kl[64 * 128];
    __shared__ __attribute__((aligned(16))) s16 Vl[128 * 64];
    int bid0 = blockIdx.x;
    int bid = ((bid0 & 7) << 7) | (bid0 >> 3);   // XCD swizzle (1024 blocks)
    int qt = bid & 31;
    int bh = bid >> 5;
    int q0 = qt << 6;
    int t = threadIdx.x;
    int wid = t >> 6, lane = t & 63;
    int c = lane & 15, g = lane >> 4;

    const s16* qrow = qb + ((size_t)bh * TSEQ + q0 + wid * 16 + c) * HDHEAD;
    bf16x8 qf[4];
    #pragma unroll
    for (int ds = 0; ds < 4; ++ds) qf[ds] = *(const bf16x8*)(qrow + ds * 32 + g * 8);

    f32x4 zero = {0.f, 0.f, 0.f, 0.f};
    f32x4 acc_o[8];
    #pragma unroll
    for (int o = 0; o < 8; ++o) acc_o[o] = zero;
    float mrun = -INFINITY, lrun = 0.0f;
    const float sc = 0.08838834764831843f;

    int tr = t >> 4, tcb = (t & 15) << 4;
    int vr = t >> 3, vcb = (t & 7) << 4;
    const s16* ksrc = kbf + (size_t)bh * TSEQ * HDHEAD;
    const s16* vsrc = vbf + (size_t)bh * HDHEAD * TSEQ;
    int qg = q0 + wid * 16 + c;

    for (int kt = 0; kt <= qt; ++kt) {
        __syncthreads();
        #pragma unroll
        for (int rr = 0; rr < 4; ++rr) {
            int row = tr + rr * 16;
            bf16x8 kv = *(const bf16x8*)(ksrc + (size_t)(kt * 64 + row) * HDHEAD + (tcb >> 1));
            *(bf16x8*)((char*)Kl + row * 256 + (tcb ^ ((row & 7) << 4))) = kv;
        }
        #pragma unroll
        for (int rr = 0; rr < 4; ++rr) {
            int row = vr + rr * 32;
            bf16x8 vv = *(const bf16x8*)(vsrc + (size_t)row * TSEQ + kt * 64 + (vcb >> 1));
            *(bf16x8*)((char*)Vl + row * 128 + (vcb ^ ((row & 7) << 4))) = vv;
        }
        __syncthreads();

        f32x4 sacc[4];
        #pragma unroll
        for (int kb2 = 0; kb2 < 4; ++kb2) sacc[kb2] = zero;
        #pragma unroll
        for (int ds = 0; ds < 4; ++ds) {
            #pragma unroll
            for (int kb2 = 0; kb2 < 4; ++kb2) {
                int krow = kb2 * 16 + c;
                bf16x8 kf = *(const bf16x8*)((char*)Kl + krow * 256 +
                                ((ds * 64 + g * 16) ^ ((krow & 7) << 4)));
                sacc[kb2] = __builtin_amdgcn_mfma_f32_16x16x32_bf16(kf, qf[ds], sacc[kb2], 0, 0, 0);
            }
        }
        float pv[16];
        float mt = -INFINITY;
        bool diag = (kt == qt);
        #pragma unroll
        for (int kb2 = 0; kb2 < 4; ++kb2) {
            #pragma unroll
            for (int j = 0; j < 4; ++j) {
                float s = sacc[kb2][j] * sc;
                if (diag && (kt * 64 + kb2 * 16 + g * 4 + j) > qg) s = -INFINITY;
                pv[kb2 * 4 + j] = s;
                mt = fmaxf(mt, s);
            }
        }
        mt = fmaxf(mt, __shfl_xor(mt, 16));
        mt = fmaxf(mt, __shfl_xor(mt, 32));
        float mnew = fmaxf(mrun, mt);
        float corr = __expf(mrun - mnew);
        float ls = 0.0f;
        #pragma unroll
        for (int i = 0; i < 16; ++i) { float p = __expf(pv[i] - mnew); pv[i] = p; ls += p; }
        ls += __shfl_xor(ls, 16);
        ls += __shfl_xor(ls, 32);
        lrun = lrun * corr + ls;
        mrun = mnew;
        #pragma unroll
        for (int o = 0; o < 8; ++o)
            #pragma unroll
            for (int j = 0; j < 4; ++j) acc_o[o][j] *= corr;

        unsigned dpk[8];
        #pragma unroll
        for (int kb2 = 0; kb2 < 4; ++kb2) {
            dpk[kb2 * 2]     = (unsigned)f2bf(pv[kb2 * 4 + 0]) | ((unsigned)f2bf(pv[kb2 * 4 + 1]) << 16);
            dpk[kb2 * 2 + 1] = (unsigned)f2bf(pv[kb2 * 4 + 2]) | ((unsigned)f2bf(pv[kb2 * 4 + 3]) << 16);
        }
        int srcA = ((g & 1) << 5) + c;
        int srcB = srcA + 16;
        #pragma unroll
        for (int s2 = 0; s2 < 2; ++s2) {
            unsigned lo0 = (unsigned)__shfl((int)dpk[(2 * s2) * 2 + 0], srcA);
            unsigned hi0 = (unsigned)__shfl((int)dpk[(2 * s2 + 1) * 2 + 0], srcA);
            unsigned lo1 = (unsigned)__shfl((int)dpk[(2 * s2) * 2 + 1], srcA);
            unsigned hi1 = (unsigned)__shfl((int)dpk[(2 * s2 + 1) * 2 + 1], srcA);
            unsigned lo2 = (unsigned)__shfl((int)dpk[(2 * s2) * 2 + 0], srcB);
            unsigned hi2 = (unsigned)__shfl((int)dpk[(2 * s2 + 1) * 2 + 0], srcB);
            unsigned lo3 = (unsigned)__shfl((int)dpk[(2 * s2) * 2 + 1], srcB);
            unsigned hi3 = (unsigned)__shfl((int)dpk[(2 * s2 + 1) * 2 + 1], srcB);
            union { unsigned u[4]; bf16x8 v; } pf;
            pf.u[0] = (g < 2) ? lo0 : hi0;
            pf.u[1] = (g < 2) ? lo1 : hi1;
            pf.u[2] = (g < 2) ? lo2 : hi2;
            pf.u[3] = (g < 2) ? lo3 : hi3;
            #pragma unroll
            for (int o = 0; o < 8; ++o) {
                int vrow = o * 16 + c;
                bf16x8 vf = *(const bf16x8*)((char*)Vl + vrow * 128 +
                                ((s2 * 64 + g * 16) ^ ((vrow & 7) << 4)));
                acc_o[o] = __builtin_amdgcn_mfma_f32_16x16x32_bf16(vf, pf.v, acc_o[o], 0, 0, 0);
            }
        }
    }

    float inv = 1.0f / lrun;
    int bb = bh >> 4, hh = bh & 15;
    s16* yp = yb + ((size_t)bb * TSEQ + q0 + wid * 16 + c) * HDIM + hh * HDHEAD;
    #pragma unroll
    for (int o = 0; o < 8; ++o) {
        int d = o * 16 + g * 4;
        unsigned p0 = (unsigned)f2bf(acc_o[o][0] * inv) | ((unsigned)f2bf(acc_o[o][1] * inv) << 16);
        unsigned p1 = (unsigned)f2bf(acc_o[o][2] * inv) | ((unsigned)f2bf(acc_o[o][3] * inv) << 16);
        *(unsigned*)(yp + d) = p0;
        *(unsigned*)(yp + d + 2) = p1;
    }
}

extern "C" void kernel_launch(void* const* d_in, const int* in_sizes, int n_in,
                              void* d_out, int out_size, void* d_ws, size_t ws_size,
                              hipStream_t stream)
{
    const float* x     = (const float*)d_in[0];
    const float* ln1g  = (const float*)d_in[1];
    const float* ln1b  = (const float*)d_in[2];
    const float* wattn = (const float*)d_in[3];
    const float* battn = (const float*)d_in[4];
    const float* wproj = (const float*)d_in[5];
    const float* bproj = (const float*)d_in[6];
    const float* ln2g  = (const float*)d_in[7];
    const float* ln2b  = (const float*)d_in[8];
    const float* wfc   = (const float*)d_in[9];
    const float* bfc   = (const float*)d_in[10];
    const float* wfc2  = (const float*)d_in[11];
    const float* bfc2  = (const float*)d_in[12];
    float* out = (float*)d_out;

    s16* ws   = (s16*)d_ws;
    s16* wT   = ws;                        // 16,777,216 elems (max weight^T)
    s16* qbuf = wT + 16777216;             // 8,388,608
    s16* kbuf = qbuf + 8388608;            // 8,388,608
    s16* vbuf = kbuf + 8388608;            // 8,388,608 (transposed V)
    s16* hbuf = vbuf + 8388608;            // 8,388,608 (LN1 out; reused as attn y)
    s16* ybuf  = hbuf;
    s16* h2buf = qbuf;
    s16* gbuf  = kbuf;

    // 1) LN1
    ln_kernel<<<4096, 256, 0, stream>>>(x, ln1g, ln1b, hbuf);
    // 2) QKV GEMM (scatter q/k/v, v transposed)
    transpose_convert<<<dim3(6144 / 32, 2048 / 32), dim3(32, 8), 0, stream>>>(wattn, wT, 2048, 6144);
    gemm256<256, 0><<<dim3(6144 / 256, 4096 / 256), 512, 0, stream>>>(
        hbuf, wT, battn, MTOK, 6144, 2048, nullptr, nullptr, qbuf, kbuf, vbuf);
    // 3) attention
    attn_kernel<<<1024, 256, 0, stream>>>(qbuf, kbuf, vbuf, ybuf);
    // 4) proj (+residual, fp32 -> d_out)
    transpose_convert<<<dim3(2048 / 32, 2048 / 32), dim3(32, 8), 0, stream>>>(wproj, wT, 2048, 2048);
    gemm256<128, 1><<<dim3(2048 / 128, 4096 / 256), 512, 0, stream>>>(
        ybuf, wT, bproj, MTOK, 2048, 2048, out, x, nullptr, nullptr, nullptr);
    // 5) LN2
    ln_kernel<<<4096, 256, 0, stream>>>(out, ln2g, ln2b, h2buf);
    // 6) fc (+gelu, bf16)
    transpose_convert<<<dim3(8192 / 32, 2048 / 32), dim3(32, 8), 0, stream>>>(wfc, wT, 2048, 8192);
    gemm256<256, 2><<<dim3(8192 / 256, 4096 / 256), 512, 0, stream>>>(
        h2buf, wT, bfc, MTOK, 8192, 2048, nullptr, nullptr, gbuf, nullptr, nullptr);
    // 7) fc2 (+residual, fp32; reads+overwrites d_out per-element)
    transpose_convert<<<dim3(2048 / 32, 8192 / 32), dim3(32, 8), 0, stream>>>(wfc2, wT, 8192, 2048);
    gemm256<128, 1><<<dim3(2048 / 128, 4096 / 256), 512, 0, stream>>>(
        gbuf, wT, bfc2, MTOK, 2048, 8192, out, out, nullptr, nullptr, nullptr);
}